// Round 13
// baseline (548.679 us; speedup 1.0000x reference)
//
#include <hip/hip_runtime.h>
#include <hip/hip_bf16.h>
#include <stdint.h>

#define BG 64     // graphs
#define NP 256    // nodes per graph
#define DI 256    // in features
#define DO 128    // out features = clusters
#define EP 8192   // edges per graph

// ALL float tensors are FP32 (R8 probe-decoded; R9-R12 passed). Edges int32 (+int64 vote).

__device__ __forceinline__ int ldi(const void* p, size_t i, int i64) {
  return i64 ? (int)((const long long*)p)[i] : ((const int*)p)[i];
}

// ---- scatter: zero A slab, LDS deg, per-block int64 vote, A[b][dst][src]+=1 ----
__global__ __launch_bounds__(256) void k_scatter(const void* __restrict__ esrc,
                                                 const void* __restrict__ edst,
                                                 float* __restrict__ A,
                                                 float* __restrict__ deg) {
  __shared__ int cnt;
  __shared__ float sdeg[NP];
  int b = blockIdx.x, t = threadIdx.x;
  if (t == 0) cnt = 0;
  sdeg[t] = 0.f;
  __syncthreads();
  uint32_t w = ((const uint32_t*)esrc)[2 * t + 1];   // valid under int32 and int64
  if (w != 0) atomicAdd(&cnt, 1);
  float4* Az = (float4*)(A + (size_t)b * NP * NP);
  for (int i = t; i < NP * NP / 4; i += 256) Az[i] = make_float4(0.f, 0.f, 0.f, 0.f);
  __syncthreads();
  int i64 = (cnt == 0);
  const size_t base = (size_t)b * EP;
  float* Ab = A + (size_t)b * NP * NP;
  for (int e = t; e < EP; e += 256) {
    int si = ldi(esrc, base + e, i64) & (NP - 1);
    int di = ldi(edst, base + e, i64) & (NP - 1);
    atomicAdd(Ab + (size_t)di * NP + si, 1.0f);
    atomicAdd(&sdeg[di], 1.0f);
  }
  __syncthreads();
  deg[b * NP + t] = sdeg[t];
}

// ---- agg = rowscale(A @ h); tile 32x128, thread 2x8; grid (16, BG) ----
__global__ __launch_bounds__(256) void k_gemm_agg(const float* __restrict__ A,
                                                  const float* __restrict__ h,
                                                  const float* __restrict__ deg,
                                                  float* __restrict__ agg) {
  __shared__ __align__(16) float As[32][36];    // [k][r]
  __shared__ __align__(16) float Hs[32][132];   // [k][f]
  int b = blockIdx.y;
  int r0 = (blockIdx.x & 7) * 32;
  int f0 = (blockIdx.x >> 3) * 128;
  int t = threadIdx.x;
  int tr = t >> 4, tc = t & 15;   // 2 rows x 8 cols per thread
  float acc[2][8] = {};
  const float* Ab = A + (size_t)b * NP * NP;
  const float* hb = h + (size_t)b * NP * DI;
  for (int kc = 0; kc < NP; kc += 32) {
    __syncthreads();
    {  // A tile: 32 r x 32 k -> transposed [k][r]; 1 float4/thread
      int r = t >> 3;
      int ks = (t & 7) * 4;
      float4 v = *(const float4*)&Ab[(size_t)(r0 + r) * NP + kc + ks];
      As[ks + 0][r] = v.x; As[ks + 1][r] = v.y; As[ks + 2][r] = v.z; As[ks + 3][r] = v.w;
    }
    {  // H tile: 32 k x 128 f; 4 float4/thread
      int k = t >> 3;
      int fs = (t & 7) * 16;
      const float* src = &hb[(size_t)(kc + k) * DI + f0 + fs];
#pragma unroll
      for (int j = 0; j < 4; ++j)
        *(float4*)&Hs[k][fs + j * 4] = *(const float4*)(src + j * 4);
    }
    __syncthreads();
#pragma unroll
    for (int k = 0; k < 32; ++k) {
      float a0 = As[k][tr * 2], a1 = As[k][tr * 2 + 1];
      float ww[8];
      *(float4*)&ww[0] = *(const float4*)&Hs[k][tc * 8];
      *(float4*)&ww[4] = *(const float4*)&Hs[k][tc * 8 + 4];
#pragma unroll
      for (int j = 0; j < 8; ++j) { acc[0][j] += a0 * ww[j]; acc[1][j] += a1 * ww[j]; }
    }
  }
#pragma unroll
  for (int i = 0; i < 2; ++i) {
    int gi = r0 + tr * 2 + i;
    float sc = 1.0f / fmaxf(deg[b * NP + gi], 1.0f);
    float o[8];
#pragma unroll
    for (int j = 0; j < 8; ++j) o[j] = acc[i][j] * sc;
    float* dst = &agg[((size_t)b * NP + gi) * DI + f0 + tc * 8];
    *(float4*)dst = *(float4*)&o[0];
    *(float4*)(dst + 4) = *(float4*)&o[4];
  }
}

// ---- Z head GEMM fused with epilogue; tile 32 rows x 128 cols (one head per block) ----
// grid.x = 2 * (BG*NP/32): head = bx & 1 (0 feat, 1 pool), tile = bx >> 1
__global__ __launch_bounds__(256) void k_gemm_zepi(const float* __restrict__ h,
                                                   const float* __restrict__ agg,
                                                   const float* __restrict__ Wf,
                                                   const float* __restrict__ Wp,
                                                   const float* __restrict__ bfe,
                                                   const float* __restrict__ bpo,
                                                   float* __restrict__ feat,
                                                   float* __restrict__ assign) {
  __shared__ __align__(16) float Xs[32][36];    // [k][row]
  __shared__ __align__(16) float Ws[32][132];   // [k][col]
  int head = blockIdx.x & 1;
  int r0 = (blockIdx.x >> 1) * 32;
  const float* W = head ? Wp : Wf;
  const float* bp = head ? bpo : bfe;
  int t = threadIdx.x;
  int rg = t >> 4;     // 16 groups x 2 rows
  int cg = t & 15;     // 16 groups x 8 cols
  float acc[2][8] = {};
  for (int kc = 0; kc < 2 * DI; kc += 32) {
    __syncthreads();
    {  // X chunk: 32 rows x 32 k -> [k][r]
      int r = t >> 3;
      int kk = (t & 7) * 4;
      const float* src = (kc < DI) ? &h[(size_t)(r0 + r) * DI + kc + kk]
                                   : &agg[(size_t)(r0 + r) * DI + (kc - DI) + kk];
      float4 v = *(const float4*)src;
      Xs[kk + 0][r] = v.x; Xs[kk + 1][r] = v.y; Xs[kk + 2][r] = v.z; Xs[kk + 3][r] = v.w;
    }
    {  // W chunk: 32 k x 128 c
      int k = t >> 3;
      int cs = (t & 7) * 16;
      const float* src = &W[(size_t)(kc + k) * DO + cs];
#pragma unroll
      for (int j = 0; j < 4; ++j)
        *(float4*)&Ws[k][cs + j * 4] = *(const float4*)(src + j * 4);
    }
    __syncthreads();
#pragma unroll
    for (int k = 0; k < 32; ++k) {
      float a0 = Xs[k][rg * 2], a1 = Xs[k][rg * 2 + 1];
      float ww[8];
      *(float4*)&ww[0] = *(const float4*)&Ws[k][cg * 8];
      *(float4*)&ww[4] = *(const float4*)&Ws[k][cg * 8 + 4];
#pragma unroll
      for (int j = 0; j < 8; ++j) { acc[0][j] += a0 * ww[j]; acc[1][j] += a1 * ww[j]; }
    }
  }
  // epilogue (reductions across the 16 lanes sharing rg: xor bits 0..3)
  float bias[8];
#pragma unroll
  for (int j = 0; j < 8; ++j) bias[j] = bp ? bp[cg * 8 + j] : 0.f;
#pragma unroll
  for (int i = 0; i < 2; ++i) {
    int r = r0 + rg * 2 + i;
    float z[8];
    float ss = 0.f;
#pragma unroll
    for (int j = 0; j < 8; ++j) { z[j] = acc[i][j] + bias[j]; ss += z[j] * z[j]; }
    ss += __shfl_xor(ss, 1); ss += __shfl_xor(ss, 2);
    ss += __shfl_xor(ss, 4); ss += __shfl_xor(ss, 8);
    float inv = 1.0f / fmaxf(sqrtf(ss), 1e-12f);
    float v[8];
#pragma unroll
    for (int j = 0; j < 8; ++j) v[j] = fmaxf(z[j] * inv, 0.f);
    if (head == 0) {
      float* dst = &feat[(size_t)r * DO + cg * 8];
      *(float4*)dst = *(float4*)&v[0];
      *(float4*)(dst + 4) = *(float4*)&v[4];
    } else {
      float mx = v[0];
#pragma unroll
      for (int j = 1; j < 8; ++j) mx = fmaxf(mx, v[j]);
      mx = fmaxf(mx, __shfl_xor(mx, 1)); mx = fmaxf(mx, __shfl_xor(mx, 2));
      mx = fmaxf(mx, __shfl_xor(mx, 4)); mx = fmaxf(mx, __shfl_xor(mx, 8));
      float e[8], s = 0.f;
#pragma unroll
      for (int j = 0; j < 8; ++j) { e[j] = __expf(v[j] - mx); s += e[j]; }
      s += __shfl_xor(s, 1); s += __shfl_xor(s, 2);
      s += __shfl_xor(s, 4); s += __shfl_xor(s, 8);
      float is = 1.0f / s;
      float o[8];
#pragma unroll
      for (int j = 0; j < 8; ++j) o[j] = e[j] * is;
      float* dst = &assign[(size_t)r * DO + cg * 8];
      *(float4*)dst = *(float4*)&o[0];
      *(float4*)(dst + 4) = *(float4*)&o[4];
    }
  }
}

// ---- AS = A @ assign; tile 32x128, thread 2x8; grid (8, BG) ----
__global__ __launch_bounds__(256) void k_gemm_as(const float* __restrict__ A,
                                                 const float* __restrict__ assign,
                                                 float* __restrict__ AS) {
  __shared__ __align__(16) float As[32][36];
  __shared__ __align__(16) float Bs[32][132];
  int b = blockIdx.y;
  int r0 = blockIdx.x * 32;
  int t = threadIdx.x;
  int tr = t >> 4, tc = t & 15;
  float acc[2][8] = {};
  const float* Ab = A + (size_t)b * NP * NP;
  const float* asb = assign + (size_t)b * NP * DO;
  for (int kc = 0; kc < NP; kc += 32) {
    __syncthreads();
    {
      int r = t >> 3;
      int ks = (t & 7) * 4;
      float4 v = *(const float4*)&Ab[(size_t)(r0 + r) * NP + kc + ks];
      As[ks + 0][r] = v.x; As[ks + 1][r] = v.y; As[ks + 2][r] = v.z; As[ks + 3][r] = v.w;
    }
    {
      int k = t >> 3;
      int ls = (t & 7) * 16;
      const float* src = &asb[(size_t)(kc + k) * DO + ls];
#pragma unroll
      for (int j = 0; j < 4; ++j)
        *(float4*)&Bs[k][ls + j * 4] = *(const float4*)(src + j * 4);
    }
    __syncthreads();
#pragma unroll
    for (int k = 0; k < 32; ++k) {
      float a0 = As[k][tr * 2], a1 = As[k][tr * 2 + 1];
      float ww[8];
      *(float4*)&ww[0] = *(const float4*)&Bs[k][tc * 8];
      *(float4*)&ww[4] = *(const float4*)&Bs[k][tc * 8 + 4];
#pragma unroll
      for (int j = 0; j < 8; ++j) { acc[0][j] += a0 * ww[j]; acc[1][j] += a1 * ww[j]; }
    }
  }
#pragma unroll
  for (int i = 0; i < 2; ++i) {
    float* dst = &AS[((size_t)b * NP + r0 + tr * 2 + i) * DO + tc * 8];
    *(float4*)dst = *(float4*)&acc[i][0];
    *(float4*)(dst + 4) = *(float4*)&acc[i][4];
  }
}

// ---- pooling: out = assign^T @ Y; m-tile 32, thread 2x8; grid (8, BG) ----
// which = bx&1: 0 -> adjacency (writes its FULL 8192-wide rows: zeros + diag block)
//               1 -> hpool
__global__ __launch_bounds__(256) void k_pool(const float* __restrict__ assign,
                                              const float* __restrict__ AS,
                                              const float* __restrict__ feat,
                                              float* __restrict__ adj,
                                              float* __restrict__ hpool) {
  __shared__ __align__(16) float Ps[32][36];    // [n][m]
  __shared__ __align__(16) float Ys[32][132];   // [n][d] ; reused to stage result
  int b = blockIdx.y;
  int which = blockIdx.x & 1;
  int mt = blockIdx.x >> 1;       // 0..3
  const float* Y = which ? feat : AS;
  int m0 = mt * 32;
  int t = threadIdx.x;
  int tr = t >> 4, tc = t & 15;
  float acc[2][8] = {};
  for (int nc = 0; nc < NP; nc += 32) {
    __syncthreads();
    {  // P: 32 n x 32 m
      int n = t >> 3;
      int ms = (t & 7) * 4;
      *(float4*)&Ps[n][ms] = *(const float4*)&assign[((size_t)b * NP + nc + n) * DO + m0 + ms];
    }
    {  // Y: 32 n x 128 d
      int n = t >> 3;
      int ds = (t & 7) * 16;
      const float* src = &Y[((size_t)b * NP + nc + n) * DO + ds];
#pragma unroll
      for (int j = 0; j < 4; ++j)
        *(float4*)&Ys[n][ds + j * 4] = *(const float4*)(src + j * 4);
    }
    __syncthreads();
#pragma unroll
    for (int n = 0; n < 32; ++n) {
      float a0 = Ps[n][tr * 2], a1 = Ps[n][tr * 2 + 1];
      float ww[8];
      *(float4*)&ww[0] = *(const float4*)&Ys[n][tc * 8];
      *(float4*)&ww[4] = *(const float4*)&Ys[n][tc * 8 + 4];
#pragma unroll
      for (int j = 0; j < 8; ++j) { acc[0][j] += a0 * ww[j]; acc[1][j] += a1 * ww[j]; }
    }
  }
  if (which == 1) {
#pragma unroll
    for (int i = 0; i < 2; ++i) {
      float* dst = &hpool[((size_t)b * DO + m0 + tr * 2 + i) * DO + tc * 8];
      *(float4*)dst = *(float4*)&acc[i][0];
      *(float4*)(dst + 4) = *(float4*)&acc[i][4];
    }
  } else {
    // stage result into Ys, then write full adjacency rows (zeros + diag block)
    __syncthreads();
#pragma unroll
    for (int i = 0; i < 2; ++i) {
      *(float4*)&Ys[tr * 2 + i][tc * 8] = *(float4*)&acc[i][0];
      *(float4*)&Ys[tr * 2 + i][tc * 8 + 4] = *(float4*)&acc[i][4];
    }
    __syncthreads();
    const int ROWW = BG * DO;      // 8192 floats per adj row
    for (int row = 0; row < 32; ++row) {
      float4* base = (float4*)&adj[(size_t)(b * DO + m0 + row) * ROWW];
      for (int j = t; j < ROWW / 4; j += 256) {
        float4 v = make_float4(0.f, 0.f, 0.f, 0.f);
        unsigned off = (unsigned)(j * 4 - b * DO);
        if (off < (unsigned)DO) v = *(float4*)&Ys[row][off];
        base[j] = v;
      }
    }
  }
}

extern "C" void kernel_launch(void* const* d_in, const int* in_sizes, int n_in,
                              void* d_out, int out_size, void* d_ws, size_t ws_size,
                              hipStream_t stream) {
  (void)out_size; (void)ws_size;
  int ih = -1, ie[2] = {-1, -1}, iw[2] = {-1, -1}, ib[2] = {-1, -1};
  int ne = 0, nw = 0, nb = 0;
  for (int i = 0; i < n_in; ++i) {
    long long s = in_sizes[i];
    if (s == (long long)BG * NP * DI) { if (ih < 0) ih = i; }
    else if (s == (long long)BG * EP && ne < 2) ie[ne++] = i;
    else if (s == (long long)2 * DI * DO && nw < 2) iw[nw++] = i;
    else if (s == (long long)DO && nb < 2) ib[nb++] = i;
  }
  if (ih < 0 || ne < 2 || nw < 2) {
    ih = 0;
    ie[0] = (n_in > 1) ? 1 : 0;  ie[1] = (n_in > 2) ? 2 : ie[0];
    iw[0] = (n_in > 3) ? 3 : 0;  iw[1] = (n_in > 5) ? 5 : iw[0];
    ib[0] = (n_in > 4) ? 4 : -1; ib[1] = (n_in > 6) ? 6 : -1;
    nb = (ib[1] >= 0) ? 2 : (ib[0] >= 0 ? 1 : 0);
  }
  const float* h    = (const float*)d_in[ih];
  const void* esrc  = d_in[ie[0]];
  const void* edst  = d_in[ie[1]];
  const float* Wf   = (const float*)d_in[iw[0]];
  const float* Wp   = (const float*)d_in[iw[1]];
  const float* bfe  = (nb >= 1) ? (const float*)d_in[ib[0]] : nullptr;
  const float* bpo  = (nb >= 2) ? (const float*)d_in[ib[1]] : nullptr;

  float* adj   = (float*)d_out;
  float* hpool = (float*)d_out + (size_t)(BG * DO) * (BG * DO);

  // All scratch in d_ws (~56.3 MiB; 58.8 MiB proven safe in R11/R12).
  char* wb = (char*)d_ws;
  float* A      = (float*)wb;                            // 16 MiB
  float* agg    = (float*)(wb + 16777216);               // 16 MiB
  float* feat   = (float*)(wb + 33554432);               //  8 MiB
  float* assign = (float*)(wb + 41943040);               //  8 MiB
  float* AS     = (float*)(wb + 50331648);               //  8 MiB
  float* deg    = (float*)(wb + 58720256);               // 64 KiB

  k_scatter<<<BG, 256, 0, stream>>>(esrc, edst, A, deg);
  k_gemm_agg<<<dim3(16, BG), 256, 0, stream>>>(A, h, deg, agg);
  k_gemm_zepi<<<2 * BG * NP / 32, 256, 0, stream>>>(h, agg, Wf, Wp, bfe, bpo, feat, assign);
  k_gemm_as<<<dim3(8, BG), 256, 0, stream>>>(A, assign, AS);
  k_pool<<<dim3(8, BG), 256, 0, stream>>>(assign, AS, feat, adj, hpool);
}

// Round 14
// 515.787 us; speedup vs baseline: 1.0638x; 1.0638x over previous
//
#include <hip/hip_runtime.h>
#include <hip/hip_bf16.h>
#include <stdint.h>

#define BG 64     // graphs
#define NP 256    // nodes per graph
#define DI 256    // in features
#define DO 128    // out features = clusters
#define EP 8192   // edges per graph

// ALL float tensors are FP32 (R8 probe-decoded; R9-R13 passed). Edges int32 (+int64 vote).

__device__ __forceinline__ int ldi(const void* p, size_t i, int i64) {
  return i64 ? (int)((const long long*)p)[i] : ((const int*)p)[i];
}

// ---- scatter + adjacency zeroing in one launch ----
// blocks 0..63: zero A slab + LDS deg + int64 vote + A[b][dst][src]+=1
// blocks 64..1087: zero a 256 KiB slice of the 256 MiB adjacency
__global__ __launch_bounds__(256) void k_scatter(const void* __restrict__ esrc,
                                                 const void* __restrict__ edst,
                                                 float* __restrict__ A,
                                                 float* __restrict__ deg,
                                                 float* __restrict__ adj) {
  int t = threadIdx.x;
  if (blockIdx.x >= BG) {
    // zero adjacency slice: 16384 float4 per block, 64 per thread
    int zb = blockIdx.x - BG;
    float4* base = (float4*)adj + (size_t)zb * 16384;
    const float4 z4 = make_float4(0.f, 0.f, 0.f, 0.f);
#pragma unroll
    for (int i = 0; i < 64; ++i) base[(size_t)i * 256 + t] = z4;
    return;
  }
  __shared__ int cnt;
  __shared__ float sdeg[NP];
  int b = blockIdx.x;
  if (t == 0) cnt = 0;
  sdeg[t] = 0.f;
  __syncthreads();
  uint32_t w = ((const uint32_t*)esrc)[2 * t + 1];   // valid under int32 and int64
  if (w != 0) atomicAdd(&cnt, 1);
  float4* Az = (float4*)(A + (size_t)b * NP * NP);
  for (int i = t; i < NP * NP / 4; i += 256) Az[i] = make_float4(0.f, 0.f, 0.f, 0.f);
  __syncthreads();
  int i64 = (cnt == 0);
  const size_t base = (size_t)b * EP;
  float* Ab = A + (size_t)b * NP * NP;
  for (int e = t; e < EP; e += 256) {
    int si = ldi(esrc, base + e, i64) & (NP - 1);
    int di = ldi(edst, base + e, i64) & (NP - 1);
    atomicAdd(Ab + (size_t)di * NP + si, 1.0f);
    atomicAdd(&sdeg[di], 1.0f);
  }
  __syncthreads();
  deg[b * NP + t] = sdeg[t];
}

// ---- agg = rowscale(A @ h); tile 64x128, thread 4x8; grid (8, BG)  [R12-proven] ----
__global__ __launch_bounds__(256) void k_gemm_agg(const float* __restrict__ A,
                                                  const float* __restrict__ h,
                                                  const float* __restrict__ deg,
                                                  float* __restrict__ agg) {
  __shared__ __align__(16) float As[32][68];    // [k][r]
  __shared__ __align__(16) float Hs[32][132];   // [k][f]
  int b = blockIdx.y;
  int r0 = (blockIdx.x & 3) * 64;
  int f0 = (blockIdx.x >> 2) * 128;
  int t = threadIdx.x;
  int tr = t >> 4, tc = t & 15;
  float acc[4][8] = {};
  const float* Ab = A + (size_t)b * NP * NP;
  const float* hb = h + (size_t)b * NP * DI;
  for (int kc = 0; kc < NP; kc += 32) {
    __syncthreads();
    {
      int r = t >> 2;
      int ks = (t & 3) * 8;
      const float* src = &Ab[(size_t)(r0 + r) * NP + kc + ks];
      float4 v0 = *(const float4*)src;
      float4 v1 = *(const float4*)(src + 4);
      As[ks + 0][r] = v0.x; As[ks + 1][r] = v0.y; As[ks + 2][r] = v0.z; As[ks + 3][r] = v0.w;
      As[ks + 4][r] = v1.x; As[ks + 5][r] = v1.y; As[ks + 6][r] = v1.z; As[ks + 7][r] = v1.w;
    }
    {
      int k = t >> 3;
      int fs = (t & 7) * 16;
      const float* src = &hb[(size_t)(kc + k) * DI + f0 + fs];
#pragma unroll
      for (int j = 0; j < 4; ++j)
        *(float4*)&Hs[k][fs + j * 4] = *(const float4*)(src + j * 4);
    }
    __syncthreads();
#pragma unroll
    for (int k = 0; k < 32; ++k) {
      float a[4], ww[8];
      *(float4*)&a[0] = *(const float4*)&As[k][tr * 4];
      *(float4*)&ww[0] = *(const float4*)&Hs[k][tc * 8];
      *(float4*)&ww[4] = *(const float4*)&Hs[k][tc * 8 + 4];
#pragma unroll
      for (int i = 0; i < 4; ++i)
#pragma unroll
        for (int j = 0; j < 8; ++j)
          acc[i][j] += a[i] * ww[j];
    }
  }
#pragma unroll
  for (int i = 0; i < 4; ++i) {
    int gi = r0 + tr * 4 + i;
    float sc = 1.0f / fmaxf(deg[b * NP + gi], 1.0f);
    float* dst = &agg[((size_t)b * NP + gi) * DI + f0 + tc * 8];
    float o0[4] = { acc[i][0] * sc, acc[i][1] * sc, acc[i][2] * sc, acc[i][3] * sc };
    float o1[4] = { acc[i][4] * sc, acc[i][5] * sc, acc[i][6] * sc, acc[i][7] * sc };
    *(float4*)dst = *(float4*)o0;
    *(float4*)(dst + 4) = *(float4*)o1;
  }
}

// ---- Z = [h|agg]@[Wf|Wp] fused epilogue; 32x256 tile  [R12-proven] ----
__global__ __launch_bounds__(256) void k_gemm_zepi(const float* __restrict__ h,
                                                   const float* __restrict__ agg,
                                                   const float* __restrict__ Wf,
                                                   const float* __restrict__ Wp,
                                                   const float* __restrict__ bfe,
                                                   const float* __restrict__ bpo,
                                                   float* __restrict__ feat,
                                                   float* __restrict__ assign) {
  __shared__ __align__(16) float Xs[32][36];    // [k][row]
  __shared__ __align__(16) float Ws[32][264];   // [k][col]
  int r0 = blockIdx.x * 32;
  int t = threadIdx.x;
  int rg = t >> 5;     // rows rg*4..+3
  int cg = t & 31;     // cols cg*8..+7
  float acc[4][8] = {};
  for (int kc = 0; kc < 2 * DI; kc += 32) {
    __syncthreads();
    {
      int r = t >> 3;
      int kk = (t & 7) * 4;
      const float* src = (kc < DI) ? &h[(size_t)(r0 + r) * DI + kc + kk]
                                   : &agg[(size_t)(r0 + r) * DI + (kc - DI) + kk];
      float4 v = *(const float4*)src;
      Xs[kk + 0][r] = v.x; Xs[kk + 1][r] = v.y; Xs[kk + 2][r] = v.z; Xs[kk + 3][r] = v.w;
    }
    {
      int k = t >> 3;
      int cbase = (t & 7) * 32;
      const float* srcW = (cbase < DO) ? &Wf[(size_t)(kc + k) * DO + cbase]
                                       : &Wp[(size_t)(kc + k) * DO + cbase - DO];
#pragma unroll
      for (int j = 0; j < 8; ++j)
        *(float4*)&Ws[k][cbase + j * 4] = *(const float4*)(srcW + j * 4);
    }
    __syncthreads();
#pragma unroll
    for (int kk = 0; kk < 32; ++kk) {
      float a[4], ww[8];
      *(float4*)&a[0] = *(const float4*)&Xs[kk][rg * 4];
      *(float4*)&ww[0] = *(const float4*)&Ws[kk][cg * 8];
      *(float4*)&ww[4] = *(const float4*)&Ws[kk][cg * 8 + 4];
#pragma unroll
      for (int i = 0; i < 4; ++i)
#pragma unroll
        for (int j = 0; j < 8; ++j)
          acc[i][j] += a[i] * ww[j];
    }
  }
  int half = cg >> 4;
  float bias[8];
  {
    const float* bp = half ? bpo : bfe;
#pragma unroll
    for (int j = 0; j < 8; ++j) bias[j] = bp ? bp[(cg * 8 + j) & (DO - 1)] : 0.f;
  }
#pragma unroll
  for (int i = 0; i < 4; ++i) {
    int r = r0 + rg * 4 + i;
    float z[8];
    float ss = 0.f;
#pragma unroll
    for (int j = 0; j < 8; ++j) { z[j] = acc[i][j] + bias[j]; ss += z[j] * z[j]; }
    ss += __shfl_xor(ss, 1); ss += __shfl_xor(ss, 2);
    ss += __shfl_xor(ss, 4); ss += __shfl_xor(ss, 8);
    float inv = 1.0f / fmaxf(sqrtf(ss), 1e-12f);
    float v[8];
#pragma unroll
    for (int j = 0; j < 8; ++j) v[j] = fmaxf(z[j] * inv, 0.f);
    if (half == 0) {
      float* dst = &feat[(size_t)r * DO + cg * 8];
      *(float4*)dst = *(float4*)&v[0];
      *(float4*)(dst + 4) = *(float4*)&v[4];
    } else {
      float mx = v[0];
#pragma unroll
      for (int j = 1; j < 8; ++j) mx = fmaxf(mx, v[j]);
      mx = fmaxf(mx, __shfl_xor(mx, 1)); mx = fmaxf(mx, __shfl_xor(mx, 2));
      mx = fmaxf(mx, __shfl_xor(mx, 4)); mx = fmaxf(mx, __shfl_xor(mx, 8));
      float e[8], s = 0.f;
#pragma unroll
      for (int j = 0; j < 8; ++j) { e[j] = __expf(v[j] - mx); s += e[j]; }
      s += __shfl_xor(s, 1); s += __shfl_xor(s, 2);
      s += __shfl_xor(s, 4); s += __shfl_xor(s, 8);
      float is = 1.0f / s;
      float o[8];
#pragma unroll
      for (int j = 0; j < 8; ++j) o[j] = e[j] * is;
      float* dst = &assign[(size_t)r * DO + (cg - 16) * 8];
      *(float4*)dst = *(float4*)&o[0];
      *(float4*)(dst + 4) = *(float4*)&o[4];
    }
  }
}

// ---- AS = A @ assign; tile 32x128, thread 2x8; grid (8, BG) = 2 blocks/CU ----
__global__ __launch_bounds__(256) void k_gemm_as(const float* __restrict__ A,
                                                 const float* __restrict__ assign,
                                                 float* __restrict__ AS) {
  __shared__ __align__(16) float As[32][36];
  __shared__ __align__(16) float Bs[32][132];
  int b = blockIdx.y;
  int r0 = blockIdx.x * 32;
  int t = threadIdx.x;
  int tr = t >> 4, tc = t & 15;
  float acc[2][8] = {};
  const float* Ab = A + (size_t)b * NP * NP;
  const float* asb = assign + (size_t)b * NP * DO;
  for (int kc = 0; kc < NP; kc += 32) {
    __syncthreads();
    {
      int r = t >> 3;
      int ks = (t & 7) * 4;
      float4 v = *(const float4*)&Ab[(size_t)(r0 + r) * NP + kc + ks];
      As[ks + 0][r] = v.x; As[ks + 1][r] = v.y; As[ks + 2][r] = v.z; As[ks + 3][r] = v.w;
    }
    {
      int k = t >> 3;
      int ls = (t & 7) * 16;
      const float* src = &asb[(size_t)(kc + k) * DO + ls];
#pragma unroll
      for (int j = 0; j < 4; ++j)
        *(float4*)&Bs[k][ls + j * 4] = *(const float4*)(src + j * 4);
    }
    __syncthreads();
#pragma unroll
    for (int k = 0; k < 32; ++k) {
      float a0 = As[k][tr * 2], a1 = As[k][tr * 2 + 1];
      float ww[8];
      *(float4*)&ww[0] = *(const float4*)&Bs[k][tc * 8];
      *(float4*)&ww[4] = *(const float4*)&Bs[k][tc * 8 + 4];
#pragma unroll
      for (int j = 0; j < 8; ++j) { acc[0][j] += a0 * ww[j]; acc[1][j] += a1 * ww[j]; }
    }
  }
#pragma unroll
  for (int i = 0; i < 2; ++i) {
    float* dst = &AS[((size_t)b * NP + r0 + tr * 2 + i) * DO + tc * 8];
    *(float4*)dst = *(float4*)&acc[i][0];
    *(float4*)(dst + 4) = *(float4*)&acc[i][4];
  }
}

// ---- pooling: out = assign^T @ Y ; 64x128 tile; which 0 -> adj diag, 1 -> hpool  [R12] --
__global__ __launch_bounds__(256) void k_pool(const float* __restrict__ assign,
                                              const float* __restrict__ AS,
                                              const float* __restrict__ feat,
                                              float* __restrict__ adj,
                                              float* __restrict__ hpool) {
  __shared__ __align__(16) float Ps[32][68];
  __shared__ __align__(16) float Ys[32][132];
  int b = blockIdx.y;
  int mt = blockIdx.x & 1;
  int which = blockIdx.x >> 1;
  const float* Y = which ? feat : AS;
  int m0 = mt * 64;
  int t = threadIdx.x;
  int tr = t >> 4, tc = t & 15;
  float acc[4][8] = {};
  for (int nc = 0; nc < NP; nc += 32) {
    __syncthreads();
    {
      int n = t >> 3;
      int mseg = (t & 7) * 8;
      const float* src = &assign[((size_t)b * NP + nc + n) * DO + m0 + mseg];
      *(float4*)&Ps[n][mseg] = *(const float4*)src;
      *(float4*)&Ps[n][mseg + 4] = *(const float4*)(src + 4);
    }
    {
      int n = t >> 3;
      int ds = (t & 7) * 16;
      const float* src = &Y[((size_t)b * NP + nc + n) * DO + ds];
#pragma unroll
      for (int j = 0; j < 4; ++j)
        *(float4*)&Ys[n][ds + j * 4] = *(const float4*)(src + j * 4);
    }
    __syncthreads();
#pragma unroll
    for (int n = 0; n < 32; ++n) {
      float a[4], ww[8];
      *(float4*)&a[0] = *(const float4*)&Ps[n][tr * 4];
      *(float4*)&ww[0] = *(const float4*)&Ys[n][tc * 8];
      *(float4*)&ww[4] = *(const float4*)&Ys[n][tc * 8 + 4];
#pragma unroll
      for (int i = 0; i < 4; ++i)
#pragma unroll
        for (int j = 0; j < 8; ++j)
          acc[i][j] += a[i] * ww[j];
    }
  }
  if (which == 0) {  // adjacency diagonal block into pre-zeroed adj
#pragma unroll
    for (int i = 0; i < 4; ++i) {
      float* dst = &adj[(size_t)(b * DO + m0 + tr * 4 + i) * (BG * DO) + b * DO + tc * 8];
      *(float4*)dst = *(float4*)&acc[i][0];
      *(float4*)(dst + 4) = *(float4*)&acc[i][4];
    }
  } else {
#pragma unroll
    for (int i = 0; i < 4; ++i) {
      float* dst = &hpool[((size_t)b * DO + m0 + tr * 4 + i) * DO + tc * 8];
      *(float4*)dst = *(float4*)&acc[i][0];
      *(float4*)(dst + 4) = *(float4*)&acc[i][4];
    }
  }
}

extern "C" void kernel_launch(void* const* d_in, const int* in_sizes, int n_in,
                              void* d_out, int out_size, void* d_ws, size_t ws_size,
                              hipStream_t stream) {
  (void)out_size; (void)ws_size;
  int ih = -1, ie[2] = {-1, -1}, iw[2] = {-1, -1}, ib[2] = {-1, -1};
  int ne = 0, nw = 0, nb = 0;
  for (int i = 0; i < n_in; ++i) {
    long long s = in_sizes[i];
    if (s == (long long)BG * NP * DI) { if (ih < 0) ih = i; }
    else if (s == (long long)BG * EP && ne < 2) ie[ne++] = i;
    else if (s == (long long)2 * DI * DO && nw < 2) iw[nw++] = i;
    else if (s == (long long)DO && nb < 2) ib[nb++] = i;
  }
  if (ih < 0 || ne < 2 || nw < 2) {
    ih = 0;
    ie[0] = (n_in > 1) ? 1 : 0;  ie[1] = (n_in > 2) ? 2 : ie[0];
    iw[0] = (n_in > 3) ? 3 : 0;  iw[1] = (n_in > 5) ? 5 : iw[0];
    ib[0] = (n_in > 4) ? 4 : -1; ib[1] = (n_in > 6) ? 6 : -1;
    nb = (ib[1] >= 0) ? 2 : (ib[0] >= 0 ? 1 : 0);
  }
  const float* h    = (const float*)d_in[ih];
  const void* esrc  = d_in[ie[0]];
  const void* edst  = d_in[ie[1]];
  const float* Wf   = (const float*)d_in[iw[0]];
  const float* Wp   = (const float*)d_in[iw[1]];
  const float* bfe  = (nb >= 1) ? (const float*)d_in[ib[0]] : nullptr;
  const float* bpo  = (nb >= 2) ? (const float*)d_in[ib[1]] : nullptr;

  float* adj   = (float*)d_out;
  float* hpool = (float*)d_out + (size_t)(BG * DO) * (BG * DO);

  // Scratch in d_ws (~56.3 MiB; proven safe R11-R13).
  char* wb = (char*)d_ws;
  float* A      = (float*)wb;                            // 16 MiB
  float* agg    = (float*)(wb + 16777216);               // 16 MiB
  float* feat   = (float*)(wb + 33554432);               //  8 MiB
  float* assign = (float*)(wb + 41943040);               //  8 MiB
  float* AS     = (float*)(wb + 50331648);               //  8 MiB
  float* deg    = (float*)(wb + 58720256);               // 64 KiB

  k_scatter<<<BG + 1024, 256, 0, stream>>>(esrc, edst, A, deg, adj);
  k_gemm_agg<<<dim3(8, BG), 256, 0, stream>>>(A, h, deg, agg);
  k_gemm_zepi<<<BG * NP / 32, 256, 0, stream>>>(h, agg, Wf, Wp, bfe, bpo, feat, assign);
  k_gemm_as<<<dim3(8, BG), 256, 0, stream>>>(A, assign, AS);
  k_pool<<<dim3(4, BG), 256, 0, stream>>>(assign, AS, feat, adj, hpool);
}

// Round 15
// 474.087 us; speedup vs baseline: 1.1573x; 1.0880x over previous
//
#include <hip/hip_runtime.h>
#include <hip/hip_bf16.h>
#include <stdint.h>

#define BG 64     // graphs
#define NP 256    // nodes per graph
#define DI 256    // in features
#define DO 128    // out features = clusters
#define EP 8192   // edges per graph

// ALL float tensors are FP32 (R8 probe-decoded; R9-R14 passed). Edges int32 (+int64 vote).

typedef __attribute__((ext_vector_type(8))) short short8;   // 8 bf16 (4 VGPRs)
typedef __attribute__((ext_vector_type(4))) float float4v;  // MFMA accumulator

__device__ __forceinline__ int ldi(const void* p, size_t i, int i64) {
  return i64 ? (int)((const long long*)p)[i] : ((const int*)p)[i];
}

// fp32 -> bf16 bits, round-to-nearest-even
__device__ __forceinline__ short f2b(float x) {
  union { float f; unsigned u; } c; c.f = x;
  unsigned r = c.u + 0x7FFFu + ((c.u >> 16) & 1u);
  return (short)(r >> 16);
}

// ---- scatter: zero A slab inline, int64 vote, A[b][dst][src]+=1, deg via global atomics
__global__ void k_scatter(const void* __restrict__ esrc, const void* __restrict__ edst,
                          float* __restrict__ A, float* __restrict__ deg) {
  __shared__ int cnt;
  int b = blockIdx.x, t = threadIdx.x;
  if (t == 0) cnt = 0;
  __syncthreads();
  uint32_t w = ((const uint32_t*)esrc)[2 * t + 1];   // valid under int32 and int64
  if (w != 0) atomicAdd(&cnt, 1);
  float4* Az = (float4*)(A + (size_t)b * NP * NP);
  for (int i = t; i < NP * NP / 4; i += 256) Az[i] = make_float4(0.f, 0.f, 0.f, 0.f);
  deg[b * NP + t] = 0.f;
  __syncthreads();
  int i64 = (cnt == 0);
  const size_t base = (size_t)b * EP;
  float* Ab = A + (size_t)b * NP * NP;
  float* degb = deg + b * NP;
  for (int e = t; e < EP; e += 256) {
    int si = ldi(esrc, base + e, i64) & (NP - 1);
    int di = ldi(edst, base + e, i64) & (NP - 1);
    atomicAdd(Ab + (size_t)di * NP + si, 1.0f);
    atomicAdd(degb + di, 1.0f);
  }
}

// ---- Wt[n][k] = bf16(W_head(n)[k][n&127]); Wt is [256][512] shorts, k-contiguous ----
__global__ __launch_bounds__(256) void k_wt(const float* __restrict__ Wf,
                                            const float* __restrict__ Wp,
                                            short* __restrict__ Wt) {
  __shared__ __align__(16) float T[32][132];
  int b = blockIdx.x;          // 0..31
  int head = b >> 4;
  int k0 = (b & 15) * 32;
  const float* W = head ? Wp : Wf;
  int t = threadIdx.x;
  {
    int k = t >> 3, fs = (t & 7) * 16;
    const float* src = &W[(size_t)(k0 + k) * DO + fs];
#pragma unroll
    for (int j = 0; j < 4; ++j)
      *(float4*)&T[k][fs + j * 4] = *(const float4*)(src + j * 4);
  }
  __syncthreads();
  int f = t & 127, kh = (t >> 7) * 16;
  __align__(16) short tmp[16];
#pragma unroll
  for (int i = 0; i < 16; ++i) tmp[i] = f2b(T[kh + i][f]);
  short* dst = &Wt[((size_t)head * DO + f) * 512 + k0 + kh];
  *(short8*)dst = *(short8*)&tmp[0];
  *(short8*)(dst + 8) = *(short8*)&tmp[8];
}

// ---- agg = rowscale(A @ h); tile 64x128, thread 4x8; grid (8, BG)  [508-proven] ----
__global__ __launch_bounds__(256) void k_gemm_agg(const float* __restrict__ A,
                                                  const float* __restrict__ h,
                                                  const float* __restrict__ deg,
                                                  float* __restrict__ agg) {
  __shared__ __align__(16) float As[32][68];
  __shared__ __align__(16) float Hs[32][132];
  int b = blockIdx.y;
  int r0 = (blockIdx.x & 3) * 64;
  int f0 = (blockIdx.x >> 2) * 128;
  int t = threadIdx.x;
  int tr = t >> 4, tc = t & 15;
  float acc[4][8] = {};
  const float* Ab = A + (size_t)b * NP * NP;
  const float* hb = h + (size_t)b * NP * DI;
  for (int kc = 0; kc < NP; kc += 32) {
    __syncthreads();
    {
      int r = t >> 2;
      int ks = (t & 3) * 8;
      const float* src = &Ab[(size_t)(r0 + r) * NP + kc + ks];
      float4 v0 = *(const float4*)src;
      float4 v1 = *(const float4*)(src + 4);
      As[ks + 0][r] = v0.x; As[ks + 1][r] = v0.y; As[ks + 2][r] = v0.z; As[ks + 3][r] = v0.w;
      As[ks + 4][r] = v1.x; As[ks + 5][r] = v1.y; As[ks + 6][r] = v1.z; As[ks + 7][r] = v1.w;
    }
    {
      int k = t >> 3;
      int fs = (t & 7) * 16;
      const float* src = &hb[(size_t)(kc + k) * DI + f0 + fs];
#pragma unroll
      for (int j = 0; j < 4; ++j)
        *(float4*)&Hs[k][fs + j * 4] = *(const float4*)(src + j * 4);
    }
    __syncthreads();
#pragma unroll
    for (int k = 0; k < 32; ++k) {
      float a[4], ww[8];
      *(float4*)&a[0] = *(const float4*)&As[k][tr * 4];
      *(float4*)&ww[0] = *(const float4*)&Hs[k][tc * 8];
      *(float4*)&ww[4] = *(const float4*)&Hs[k][tc * 8 + 4];
#pragma unroll
      for (int i = 0; i < 4; ++i)
#pragma unroll
        for (int j = 0; j < 8; ++j)
          acc[i][j] += a[i] * ww[j];
    }
  }
#pragma unroll
  for (int i = 0; i < 4; ++i) {
    int gi = r0 + tr * 4 + i;
    float sc = 1.0f / fmaxf(deg[b * NP + gi], 1.0f);
    float* dst = &agg[((size_t)b * NP + gi) * DI + f0 + tc * 8];
    float o0[4] = { acc[i][0] * sc, acc[i][1] * sc, acc[i][2] * sc, acc[i][3] * sc };
    float o1[4] = { acc[i][4] * sc, acc[i][5] * sc, acc[i][6] * sc, acc[i][7] * sc };
    *(float4*)dst = *(float4*)o0;
    *(float4*)(dst + 4) = *(float4*)o1;
  }
}

// ---- MFMA zepi: Z = [h|agg]@[Wf|Wp] (bf16 16x16x32), fused bias/norm/relu/softmax ----
// block = 32 rows x 256 cols; wave w: row-tile rt=w&1, head ch=w>>1 (8 col-tiles of 16).
__global__ __launch_bounds__(256) void k_zepi_mfma(const float* __restrict__ h,
                                                   const float* __restrict__ agg,
                                                   const short* __restrict__ Wt,
                                                   const float* __restrict__ bfe,
                                                   const float* __restrict__ bpo,
                                                   float* __restrict__ feat,
                                                   float* __restrict__ assign) {
  __shared__ __align__(16) short Xs[32][40];    // [r][k] bf16, row stride 80 B (16B-aligned)
  int r0 = blockIdx.x * 32;
  int t = threadIdx.x;
  int wave = t >> 6, lane = t & 63;
  int rt = wave & 1, ch = wave >> 1;
  int m = lane & 15, q = lane >> 4;             // frag row/col index, k-quad
  float4v acc[8];
#pragma unroll
  for (int i = 0; i < 8; ++i) acc[i] = (float4v){0.f, 0.f, 0.f, 0.f};

  for (int kc = 0; kc < 2 * DI; kc += 32) {
    __syncthreads();
    {  // stage X chunk (32 rows x 32 k) as bf16
      int r = t >> 3, k4 = (t & 7) * 4;
      const float* src = (kc < DI) ? &h[(size_t)(r0 + r) * DI + kc + k4]
                                   : &agg[(size_t)(r0 + r) * DI + (kc - DI) + k4];
      float4 v = *(const float4*)src;
      Xs[r][k4 + 0] = f2b(v.x); Xs[r][k4 + 1] = f2b(v.y);
      Xs[r][k4 + 2] = f2b(v.z); Xs[r][k4 + 3] = f2b(v.w);
    }
    __syncthreads();
    short8 afrag = *(const short8*)&Xs[rt * 16 + m][q * 8];
#pragma unroll
    for (int tt = 0; tt < 8; ++tt) {
      int n = ch * 128 + tt * 16 + m;
      short8 bfrag = *(const short8*)&Wt[(size_t)n * 512 + kc + q * 8];
      acc[tt] = __builtin_amdgcn_mfma_f32_16x16x32_bf16(afrag, bfrag, acc[tt], 0, 0, 0);
    }
  }

  // epilogue: C/D layout col = tt*16+m, row = q*4+reg (within row-tile)
  const float* bp = ch ? bpo : bfe;
  float bias[8];
#pragma unroll
  for (int tt = 0; tt < 8; ++tt) bias[tt] = bp ? bp[tt * 16 + m] : 0.f;
#pragma unroll
  for (int reg = 0; reg < 4; ++reg) {
    int row = r0 + rt * 16 + q * 4 + reg;
    float z[8];
    float ss = 0.f;
#pragma unroll
    for (int tt = 0; tt < 8; ++tt) { z[tt] = acc[tt][reg] + bias[tt]; ss += z[tt] * z[tt]; }
    ss += __shfl_xor(ss, 1); ss += __shfl_xor(ss, 2);
    ss += __shfl_xor(ss, 4); ss += __shfl_xor(ss, 8);
    float inv = 1.0f / fmaxf(sqrtf(ss), 1e-12f);
    float v[8];
#pragma unroll
    for (int tt = 0; tt < 8; ++tt) v[tt] = fmaxf(z[tt] * inv, 0.f);
    if (ch == 0) {
#pragma unroll
      for (int tt = 0; tt < 8; ++tt) feat[(size_t)row * DO + tt * 16 + m] = v[tt];
    } else {
      float mx = v[0];
#pragma unroll
      for (int tt = 1; tt < 8; ++tt) mx = fmaxf(mx, v[tt]);
      mx = fmaxf(mx, __shfl_xor(mx, 1)); mx = fmaxf(mx, __shfl_xor(mx, 2));
      mx = fmaxf(mx, __shfl_xor(mx, 4)); mx = fmaxf(mx, __shfl_xor(mx, 8));
      float e[8], s = 0.f;
#pragma unroll
      for (int tt = 0; tt < 8; ++tt) { e[tt] = __expf(v[tt] - mx); s += e[tt]; }
      s += __shfl_xor(s, 1); s += __shfl_xor(s, 2);
      s += __shfl_xor(s, 4); s += __shfl_xor(s, 8);
      float is = 1.0f / s;
#pragma unroll
      for (int tt = 0; tt < 8; ++tt) assign[(size_t)row * DO + tt * 16 + m] = e[tt] * is;
    }
  }
}

// ---- AS = A @ assign; tile 64x128, thread 4x8; grid (4, BG)  [508-proven] ----
__global__ __launch_bounds__(256) void k_gemm_as(const float* __restrict__ A,
                                                 const float* __restrict__ assign,
                                                 float* __restrict__ AS) {
  __shared__ __align__(16) float As[32][68];
  __shared__ __align__(16) float Bs[32][132];
  int b = blockIdx.y;
  int r0 = blockIdx.x * 64;
  int t = threadIdx.x;
  int tr = t >> 4, tc = t & 15;
  float acc[4][8] = {};
  const float* Ab = A + (size_t)b * NP * NP;
  const float* asb = assign + (size_t)b * NP * DO;
  for (int kc = 0; kc < NP; kc += 32) {
    __syncthreads();
    {
      int r = t >> 2;
      int ks = (t & 3) * 8;
      const float* src = &Ab[(size_t)(r0 + r) * NP + kc + ks];
      float4 v0 = *(const float4*)src;
      float4 v1 = *(const float4*)(src + 4);
      As[ks + 0][r] = v0.x; As[ks + 1][r] = v0.y; As[ks + 2][r] = v0.z; As[ks + 3][r] = v0.w;
      As[ks + 4][r] = v1.x; As[ks + 5][r] = v1.y; As[ks + 6][r] = v1.z; As[ks + 7][r] = v1.w;
    }
    {
      int k = t >> 3;
      int ls = (t & 7) * 16;
      const float* src = &asb[(size_t)(kc + k) * DO + ls];
#pragma unroll
      for (int j = 0; j < 4; ++j)
        *(float4*)&Bs[k][ls + j * 4] = *(const float4*)(src + j * 4);
    }
    __syncthreads();
#pragma unroll
    for (int k = 0; k < 32; ++k) {
      float a[4], ww[8];
      *(float4*)&a[0] = *(const float4*)&As[k][tr * 4];
      *(float4*)&ww[0] = *(const float4*)&Bs[k][tc * 8];
      *(float4*)&ww[4] = *(const float4*)&Bs[k][tc * 8 + 4];
#pragma unroll
      for (int i = 0; i < 4; ++i)
#pragma unroll
        for (int j = 0; j < 8; ++j)
          acc[i][j] += a[i] * ww[j];
    }
  }
#pragma unroll
  for (int i = 0; i < 4; ++i) {
    float* dst = &AS[((size_t)b * NP + r0 + tr * 4 + i) * DO + tc * 8];
    *(float4*)dst = *(float4*)&acc[i][0];
    *(float4*)(dst + 4) = *(float4*)&acc[i][4];
  }
}

// ---- pooling: out = assign^T @ Y ; 64x128 tile; which 0 -> adj diag, 1 -> hpool [508] --
__global__ __launch_bounds__(256) void k_pool(const float* __restrict__ assign,
                                              const float* __restrict__ AS,
                                              const float* __restrict__ feat,
                                              float* __restrict__ adj,
                                              float* __restrict__ hpool) {
  __shared__ __align__(16) float Ps[32][68];
  __shared__ __align__(16) float Ys[32][132];
  int b = blockIdx.y;
  int mt = blockIdx.x & 1;
  int which = blockIdx.x >> 1;
  const float* Y = which ? feat : AS;
  int m0 = mt * 64;
  int t = threadIdx.x;
  int tr = t >> 4, tc = t & 15;
  float acc[4][8] = {};
  for (int nc = 0; nc < NP; nc += 32) {
    __syncthreads();
    {
      int n = t >> 3;
      int mseg = (t & 7) * 8;
      const float* src = &assign[((size_t)b * NP + nc + n) * DO + m0 + mseg];
      *(float4*)&Ps[n][mseg] = *(const float4*)src;
      *(float4*)&Ps[n][mseg + 4] = *(const float4*)(src + 4);
    }
    {
      int n = t >> 3;
      int ds = (t & 7) * 16;
      const float* src = &Y[((size_t)b * NP + nc + n) * DO + ds];
#pragma unroll
      for (int j = 0; j < 4; ++j)
        *(float4*)&Ys[n][ds + j * 4] = *(const float4*)(src + j * 4);
    }
    __syncthreads();
#pragma unroll
    for (int n = 0; n < 32; ++n) {
      float a[4], ww[8];
      *(float4*)&a[0] = *(const float4*)&Ps[n][tr * 4];
      *(float4*)&ww[0] = *(const float4*)&Ys[n][tc * 8];
      *(float4*)&ww[4] = *(const float4*)&Ys[n][tc * 8 + 4];
#pragma unroll
      for (int i = 0; i < 4; ++i)
#pragma unroll
        for (int j = 0; j < 8; ++j)
          acc[i][j] += a[i] * ww[j];
    }
  }
  if (which == 0) {
#pragma unroll
    for (int i = 0; i < 4; ++i) {
      float* dst = &adj[(size_t)(b * DO + m0 + tr * 4 + i) * (BG * DO) + b * DO + tc * 8];
      *(float4*)dst = *(float4*)&acc[i][0];
      *(float4*)(dst + 4) = *(float4*)&acc[i][4];
    }
  } else {
#pragma unroll
    for (int i = 0; i < 4; ++i) {
      float* dst = &hpool[((size_t)b * DO + m0 + tr * 4 + i) * DO + tc * 8];
      *(float4*)dst = *(float4*)&acc[i][0];
      *(float4*)(dst + 4) = *(float4*)&acc[i][4];
    }
  }
}

extern "C" void kernel_launch(void* const* d_in, const int* in_sizes, int n_in,
                              void* d_out, int out_size, void* d_ws, size_t ws_size,
                              hipStream_t stream) {
  (void)out_size; (void)ws_size;
  int ih = -1, ie[2] = {-1, -1}, iw[2] = {-1, -1}, ib[2] = {-1, -1};
  int ne = 0, nw = 0, nb = 0;
  for (int i = 0; i < n_in; ++i) {
    long long s = in_sizes[i];
    if (s == (long long)BG * NP * DI) { if (ih < 0) ih = i; }
    else if (s == (long long)BG * EP && ne < 2) ie[ne++] = i;
    else if (s == (long long)2 * DI * DO && nw < 2) iw[nw++] = i;
    else if (s == (long long)DO && nb < 2) ib[nb++] = i;
  }
  if (ih < 0 || ne < 2 || nw < 2) {
    ih = 0;
    ie[0] = (n_in > 1) ? 1 : 0;  ie[1] = (n_in > 2) ? 2 : ie[0];
    iw[0] = (n_in > 3) ? 3 : 0;  iw[1] = (n_in > 5) ? 5 : iw[0];
    ib[0] = (n_in > 4) ? 4 : -1; ib[1] = (n_in > 6) ? 6 : -1;
    nb = (ib[1] >= 0) ? 2 : (ib[0] >= 0 ? 1 : 0);
  }
  const float* h    = (const float*)d_in[ih];
  const void* esrc  = d_in[ie[0]];
  const void* edst  = d_in[ie[1]];
  const float* Wf   = (const float*)d_in[iw[0]];
  const float* Wp   = (const float*)d_in[iw[1]];
  const float* bfe  = (nb >= 1) ? (const float*)d_in[ib[0]] : nullptr;
  const float* bpo  = (nb >= 2) ? (const float*)d_in[ib[1]] : nullptr;

  float* adj   = (float*)d_out;
  float* hpool = (float*)d_out + (size_t)(BG * DO) * (BG * DO);
  const size_t ADJ_BYTES = (size_t)(BG * DO) * (BG * DO) * sizeof(float);  // 256 MiB

  // Scratch in d_ws (~56.3 MiB + 320 KiB; harness poison fills indicate ws >= 1 GiB).
  char* wb = (char*)d_ws;
  float* A      = (float*)wb;                            // 16 MiB
  float* agg    = (float*)(wb + 16777216);               // 16 MiB
  float* feat   = (float*)(wb + 33554432);               //  8 MiB
  float* assign = (float*)(wb + 41943040);               //  8 MiB
  float* AS     = (float*)(wb + 50331648);               //  8 MiB
  float* deg    = (float*)(wb + 58720256);               // 64 KiB
  short* Wt     = (short*)(wb + 58720256 + 65536);       // 256 KiB bf16 W^T

  hipMemsetAsync(adj, 0, ADJ_BYTES, stream);
  k_wt<<<32, 256, 0, stream>>>(Wf, Wp, Wt);
  k_scatter<<<BG, 256, 0, stream>>>(esrc, edst, A, deg);
  k_gemm_agg<<<dim3(8, BG), 256, 0, stream>>>(A, h, deg, agg);
  k_zepi_mfma<<<BG * NP / 32, 256, 0, stream>>>(h, agg, Wt, bfe, bpo, feat, assign);
  k_gemm_as<<<dim3(4, BG), 256, 0, stream>>>(A, assign, AS);
  k_pool<<<dim3(4, BG), 256, 0, stream>>>(assign, AS, feat, adj, hpool);
}